// Round 3
// baseline (505.352 us; speedup 1.0000x reference)
//
#include <hip/hip_runtime.h>
#include <math.h>

// ---------------- setup kernels: degree, rsqrt, scan, CSR fill ----------------

__global__ void count_kernel(const int* __restrict__ row, int* __restrict__ cnt, int E) {
    int e = blockIdx.x * 256 + threadIdx.x;
    if (e < E) atomicAdd(&cnt[row[e]], 1);
}

// exclusive scan of cnt[N] -> excl[N]; also computes dis = rsqrt(deg+1)
__global__ void scan1_kernel(const int* __restrict__ cnt, int* __restrict__ excl,
                             int* __restrict__ blksum, float* __restrict__ dis, int N) {
    __shared__ int sdata[256];
    int t = threadIdx.x;
    int base = blockIdx.x * 1024 + t * 4;
    int v0 = (base + 0 < N) ? cnt[base + 0] : 0;
    int v1 = (base + 1 < N) ? cnt[base + 1] : 0;
    int v2 = (base + 2 < N) ? cnt[base + 2] : 0;
    int v3 = (base + 3 < N) ? cnt[base + 3] : 0;
    if (base + 0 < N) dis[base + 0] = rsqrtf((float)v0 + 1.0f);
    if (base + 1 < N) dis[base + 1] = rsqrtf((float)v1 + 1.0f);
    if (base + 2 < N) dis[base + 2] = rsqrtf((float)v2 + 1.0f);
    if (base + 3 < N) dis[base + 3] = rsqrtf((float)v3 + 1.0f);
    int tot = v0 + v1 + v2 + v3;
    sdata[t] = tot;
    __syncthreads();
    for (int o = 1; o < 256; o <<= 1) {
        int x = (t >= o) ? sdata[t - o] : 0;
        __syncthreads();
        sdata[t] += x;
        __syncthreads();
    }
    int incl = sdata[t];
    int eb = incl - tot;
    if (base + 0 < N) excl[base + 0] = eb;
    if (base + 1 < N) excl[base + 1] = eb + v0;
    if (base + 2 < N) excl[base + 2] = eb + v0 + v1;
    if (base + 3 < N) excl[base + 3] = eb + v0 + v1 + v2;
    if (t == 255) blksum[blockIdx.x] = incl;
}

__global__ void scan2_kernel(int* __restrict__ blksum, int nb) {  // 1 block, 64 threads
    int lane = threadIdx.x;
    int orig = (lane < nb) ? blksum[lane] : 0;
    int v = orig;
    for (int o = 1; o < 64; o <<= 1) { int x = __shfl_up(v, o); if (lane >= o) v += x; }
    if (lane < nb) blksum[lane] = v - orig;   // exclusive block base
}

__global__ void scan3_kernel(int* __restrict__ excl, int* __restrict__ cursor,
                             const int* __restrict__ blksum, int N, int E) {
    int i = blockIdx.x * 256 + threadIdx.x;
    if (i < N) {
        int v = excl[i] + blksum[i >> 10];
        excl[i] = v;
        cursor[i] = v;      // cursor starts at row offset -> fill atomic gives abs pos
    }
    if (i == 0) excl[N] = E;
}

__global__ void fill_kernel(const int* __restrict__ ei, int E,
                            int* __restrict__ cursor, int* __restrict__ csr_col) {
    int e = blockIdx.x * 256 + threadIdx.x;
    if (e >= E) return;
    int r = ei[e];          // destination
    int c = ei[E + e];      // source
    int pos = atomicAdd(&cursor[r], 1);
    csr_col[pos] = c;
}

// ---------------- GEMM: out[N][128] = A[N][128] @ W[128][128] ----------------

__global__ __launch_bounds__(256) void gemm_nk128(const float* __restrict__ A,
                                                  const float* __restrict__ W,
                                                  float* __restrict__ out, int N) {
    __shared__ float sA[32][64];     // A-tile transposed: sA[k][r]
    __shared__ float sW[32][128];
    const int t = threadIdx.x;
    const int tc = t & 15, tr = t >> 4;
    const int brow = blockIdx.x * 64;
    float acc[4][8];
#pragma unroll
    for (int r = 0; r < 4; ++r)
#pragma unroll
        for (int c = 0; c < 8; ++c) acc[r][c] = 0.0f;

    for (int kt = 0; kt < 128; kt += 32) {
#pragma unroll
        for (int i = 0; i < 2; ++i) {
            int idx = t + i * 256;          // 0..511
            int r = idx & 63, kq = idx >> 6;   // kq 0..7 -> k = kq*4
            int g = brow + r;
            float4 v = make_float4(0.f, 0.f, 0.f, 0.f);
            if (g < N) v = *(const float4*)&A[(size_t)g * 128 + kt + kq * 4];
            sA[kq * 4 + 0][r] = v.x; sA[kq * 4 + 1][r] = v.y;
            sA[kq * 4 + 2][r] = v.z; sA[kq * 4 + 3][r] = v.w;
        }
#pragma unroll
        for (int i = 0; i < 4; ++i) {
            int idx = t + i * 256;          // 0..1023
            int k = idx >> 5, cq = idx & 31;
            *(float4*)&sW[k][cq * 4] = *(const float4*)&W[(size_t)(kt + k) * 128 + cq * 4];
        }
        __syncthreads();
#pragma unroll
        for (int k = 0; k < 32; ++k) {
            float4 a  = *(const float4*)&sA[k][tr * 4];
            float4 b0 = *(const float4*)&sW[k][tc * 4];
            float4 b1 = *(const float4*)&sW[k][tc * 4 + 64];
            float ar[4] = {a.x, a.y, a.z, a.w};
            float bc[8] = {b0.x, b0.y, b0.z, b0.w, b1.x, b1.y, b1.z, b1.w};
#pragma unroll
            for (int r = 0; r < 4; ++r)
#pragma unroll
                for (int c = 0; c < 8; ++c)
                    acc[r][c] = fmaf(ar[r], bc[c], acc[r][c]);
        }
        __syncthreads();
    }
#pragma unroll
    for (int r = 0; r < 4; ++r) {
        int g = brow + tr * 4 + r;
        if (g < N) {
            float4 o0 = make_float4(acc[r][0], acc[r][1], acc[r][2], acc[r][3]);
            float4 o1 = make_float4(acc[r][4], acc[r][5], acc[r][6], acc[r][7]);
            *(float4*)&out[(size_t)g * 128 + tc * 4] = o0;
            *(float4*)&out[(size_t)g * 128 + tc * 4 + 64] = o1;
        }
    }
}

// ---------------- GEMM: out[N][16] = A[N][128] @ W[128][16] ----------------

__global__ __launch_bounds__(256) void gemm_nk16(const float* __restrict__ A,
                                                 const float* __restrict__ W,
                                                 float* __restrict__ out, int N) {
    __shared__ float sW[128][16];    // 8 KB
    __shared__ float sA[32][132];    // padded, 16.5 KB
    int t = threadIdx.x;
#pragma unroll
    for (int i = 0; i < 2; ++i) {
        int idx = t + i * 256;       // 0..511 float4s over 2048 floats
        *(float4*)&sW[idx >> 2][(idx & 3) * 4] = *(const float4*)&W[idx * 4];
    }
    int brow = blockIdx.x * 32;
#pragma unroll
    for (int i = 0; i < 4; ++i) {
        int idx = t + i * 256;       // 0..1023
        int rr = idx >> 5, cq = idx & 31;
        int g = brow + rr;
        float4 v = make_float4(0.f, 0.f, 0.f, 0.f);
        if (g < N) v = *(const float4*)&A[(size_t)g * 128 + cq * 4];
        *(float4*)&sA[rr][cq * 4] = v;
    }
    __syncthreads();
    int r = t >> 3;       // 0..31
    int cg = t & 7;       // cols cg*2, cg*2+1
    float a0 = 0.f, a1 = 0.f;
#pragma unroll
    for (int k = 0; k < 128; ++k) {
        float a = sA[r][k];
        float2 w = *(const float2*)&sW[k][cg * 2];
        a0 = fmaf(a, w.x, a0);
        a1 = fmaf(a, w.y, a1);
    }
    int g = brow + r;
    if (g < N) {
        out[(size_t)g * 16 + cg * 2 + 0] = a0;
        out[(size_t)g * 16 + cg * 2 + 1] = a1;
    }
}

// --------- aggregation (128 wide), XCD-feature-partitioned gather ----------
// chunk = blockIdx & 7 -> under round-robin dispatch all blocks with the same
// chunk land on the same XCD, whose 4MB L2 then holds only its 16-column slice
// of t (50000*16*4B = 3.2MB -> fully resident). One node per wave; 8 groups of
// 8 lanes each gather one edge's 64B (float2/lane); shfl_xor 8/16/32 combine.

__global__ __launch_bounds__(256) void agg128_kernel(const float* __restrict__ t,
        const int* __restrict__ csr_col, const int* __restrict__ offset,
        const float* __restrict__ dis, const float* __restrict__ bias,
        float* __restrict__ out, int N, int do_relu) {
    int chunk = blockIdx.x & 7;
    int node = (blockIdx.x >> 3) * 4 + (threadIdx.x >> 6);
    if (node >= N) return;
    int lane = threadIdx.x & 63;
    int g = lane >> 3;                 // edge group 0..7
    int colf = chunk * 16 + (lane & 7) * 2;
    float dn = dis[node];
    float2 acc = make_float2(0.f, 0.f);
    if (g == 0) {                      // self loop, weight dn^2
        float2 sv = *(const float2*)&t[(size_t)node * 128 + colf];
        float sw = dn * dn;
        acc.x = sw * sv.x; acc.y = sw * sv.y;
    }
    int s = offset[node], e = offset[node + 1];
    int j = s + g;
    for (; j + 8 < e; j += 16) {       // 16 edges (2 per group) in flight
        int c0 = csr_col[j], c1 = csr_col[j + 8];
        float2 v0 = *(const float2*)&t[(size_t)c0 * 128 + colf];
        float2 v1 = *(const float2*)&t[(size_t)c1 * 128 + colf];
        float w0 = dn * dis[c0], w1 = dn * dis[c1];
        acc.x = fmaf(w0, v0.x, acc.x); acc.y = fmaf(w0, v0.y, acc.y);
        acc.x = fmaf(w1, v1.x, acc.x); acc.y = fmaf(w1, v1.y, acc.y);
    }
    if (j < e) {
        int c = csr_col[j];
        float2 v = *(const float2*)&t[(size_t)c * 128 + colf];
        float w = dn * dis[c];
        acc.x = fmaf(w, v.x, acc.x); acc.y = fmaf(w, v.y, acc.y);
    }
    acc.x += __shfl_xor(acc.x, 8);  acc.y += __shfl_xor(acc.y, 8);
    acc.x += __shfl_xor(acc.x, 16); acc.y += __shfl_xor(acc.y, 16);
    acc.x += __shfl_xor(acc.x, 32); acc.y += __shfl_xor(acc.y, 32);
    if (g == 0) {
        float2 b = *(const float2*)&bias[colf];
        float ox = acc.x + b.x, oy = acc.y + b.y;
        if (do_relu) { ox = fmaxf(ox, 0.f); oy = fmaxf(oy, 0.f); }
        *(float2*)&out[(size_t)node * 128 + colf] = make_float2(ox, oy);
    }
}

// ------- aggregation (16 wide) + bias + log_softmax: 16 lanes per node -------

__global__ __launch_bounds__(256) void agg16_ls_kernel(const float* __restrict__ t2,
        const int* __restrict__ csr_col,
        const int* __restrict__ offset, const float* __restrict__ dis,
        const float* __restrict__ b2, float* __restrict__ out, int N) {
    int gid = blockIdx.x * 256 + threadIdx.x;
    int node = gid >> 4;
    int c = gid & 15;
    if (node >= N) return;
    float dn = dis[node];
    float acc = dn * dn * t2[(size_t)node * 16 + c];
    int s = offset[node], e = offset[node + 1];
    for (int j = s; j < e; ++j) {
        int col = csr_col[j];
        float w = dn * dis[col];
        acc = fmaf(w, t2[(size_t)col * 16 + c], acc);
    }
    float v = acc + b2[c];
    float m = v;
#pragma unroll
    for (int o = 1; o < 16; o <<= 1) m = fmaxf(m, __shfl_xor(m, o, 16));
    float ex = expf(v - m);
    float ssum = ex;
#pragma unroll
    for (int o = 1; o < 16; o <<= 1) ssum += __shfl_xor(ssum, o, 16);
    out[(size_t)node * 16 + c] = v - m - logf(ssum);
}

// ---------------------------------- launch ----------------------------------

extern "C" void kernel_launch(void* const* d_in, const int* in_sizes, int n_in,
                              void* d_out, int out_size, void* d_ws, size_t ws_size,
                              hipStream_t stream) {
    const float* x  = (const float*)d_in[0];
    const int*   ei = (const int*)d_in[1];
    const float* W0 = (const float*)d_in[2];
    const float* b0 = (const float*)d_in[3];
    const float* W1 = (const float*)d_in[4];
    const float* b1 = (const float*)d_in[5];
    const float* W2 = (const float*)d_in[6];
    const float* b2 = (const float*)d_in[7];
    int N = in_sizes[0] / 128;
    int E = in_sizes[1] / 2;
    float* out = (float*)d_out;

    char* ws = (char*)d_ws;
    size_t off = 0;
    auto alloc = [&](size_t bytes) -> void* {
        void* p = ws + off;
        off = (off + bytes + 255) & ~(size_t)255;
        return p;
    };
    float* tA      = (float*)alloc((size_t)N * 128 * 4);
    float* tB      = (float*)alloc((size_t)N * 128 * 4);
    float* t2      = (float*)alloc((size_t)N * 16 * 4);
    int*   cnt     = (int*)alloc((size_t)N * 4);
    int*   offs    = (int*)alloc((size_t)(N + 1) * 4);
    int*   cursor  = (int*)alloc((size_t)N * 4);
    int*   blksum  = (int*)alloc(64 * 4);
    float* dis     = (float*)alloc((size_t)N * 4);
    int*   csr_col = (int*)alloc((size_t)E * 4);

    hipMemsetAsync(cnt, 0, (size_t)N * 4, stream);

    int nb = (N + 1023) / 1024;   // 49 for N=50000 (must be <= 64)
    count_kernel<<<(E + 255) / 256, 256, 0, stream>>>(ei, cnt, E);
    scan1_kernel<<<nb, 256, 0, stream>>>(cnt, offs, blksum, dis, N);
    scan2_kernel<<<1, 64, 0, stream>>>(blksum, nb);
    scan3_kernel<<<(N + 255) / 256, 256, 0, stream>>>(offs, cursor, blksum, N, E);
    fill_kernel<<<(E + 255) / 256, 256, 0, stream>>>(ei, E, cursor, csr_col);

    int gemm_blocks = (N + 63) / 64;
    int agg_blocks  = ((N + 3) / 4) * 8;

    gemm_nk128<<<gemm_blocks, 256, 0, stream>>>(x, W0, tA, N);
    agg128_kernel<<<agg_blocks, 256, 0, stream>>>(tA, csr_col, offs, dis, b0, tB, N, 1);
    gemm_nk128<<<gemm_blocks, 256, 0, stream>>>(tB, W1, tA, N);
    agg128_kernel<<<agg_blocks, 256, 0, stream>>>(tA, csr_col, offs, dis, b1, tB, N, 1);
    gemm_nk16<<<(N + 31) / 32, 256, 0, stream>>>(tB, W2, t2, N);
    agg16_ls_kernel<<<(int)(((size_t)N * 16 + 255) / 256), 256, 0, stream>>>(
        t2, csr_col, offs, dis, b2, out, N);
}

// Round 4
// 266.827 us; speedup vs baseline: 1.8939x; 1.8939x over previous
//
#include <hip/hip_runtime.h>
#include <math.h>

typedef _Float16 half4 __attribute__((ext_vector_type(4)));

// ---------------- setup kernels: degree, rsqrt, scan, CSR fill ----------------

__global__ void count_kernel(const int* __restrict__ row, int* __restrict__ cnt, int E) {
    int e = blockIdx.x * 256 + threadIdx.x;
    if (e < E) atomicAdd(&cnt[row[e]], 1);
}

// exclusive scan of cnt[N] -> excl[N]; also computes dis = rsqrt(deg+1)
__global__ void scan1_kernel(const int* __restrict__ cnt, int* __restrict__ excl,
                             int* __restrict__ blksum, float* __restrict__ dis, int N) {
    __shared__ int sdata[256];
    int t = threadIdx.x;
    int base = blockIdx.x * 1024 + t * 4;
    int v0 = (base + 0 < N) ? cnt[base + 0] : 0;
    int v1 = (base + 1 < N) ? cnt[base + 1] : 0;
    int v2 = (base + 2 < N) ? cnt[base + 2] : 0;
    int v3 = (base + 3 < N) ? cnt[base + 3] : 0;
    if (base + 0 < N) dis[base + 0] = rsqrtf((float)v0 + 1.0f);
    if (base + 1 < N) dis[base + 1] = rsqrtf((float)v1 + 1.0f);
    if (base + 2 < N) dis[base + 2] = rsqrtf((float)v2 + 1.0f);
    if (base + 3 < N) dis[base + 3] = rsqrtf((float)v3 + 1.0f);
    int tot = v0 + v1 + v2 + v3;
    sdata[t] = tot;
    __syncthreads();
    for (int o = 1; o < 256; o <<= 1) {
        int x = (t >= o) ? sdata[t - o] : 0;
        __syncthreads();
        sdata[t] += x;
        __syncthreads();
    }
    int incl = sdata[t];
    int eb = incl - tot;
    if (base + 0 < N) excl[base + 0] = eb;
    if (base + 1 < N) excl[base + 1] = eb + v0;
    if (base + 2 < N) excl[base + 2] = eb + v0 + v1;
    if (base + 3 < N) excl[base + 3] = eb + v0 + v1 + v2;
    if (t == 255) blksum[blockIdx.x] = incl;
}

__global__ void scan2_kernel(int* __restrict__ blksum, int nb) {  // 1 block, 64 threads
    int lane = threadIdx.x;
    int orig = (lane < nb) ? blksum[lane] : 0;
    int v = orig;
    for (int o = 1; o < 64; o <<= 1) { int x = __shfl_up(v, o); if (lane >= o) v += x; }
    if (lane < nb) blksum[lane] = v - orig;   // exclusive block base
}

__global__ void scan3_kernel(int* __restrict__ excl, int* __restrict__ cursor,
                             const int* __restrict__ blksum, int N, int E) {
    int i = blockIdx.x * 256 + threadIdx.x;
    if (i < N) {
        int v = excl[i] + blksum[i >> 10];
        excl[i] = v;
        cursor[i] = v;      // cursor starts at row offset -> fill atomic gives abs pos
    }
    if (i == 0) excl[N] = E;
}

__global__ void fill_kernel(const int* __restrict__ ei, int E,
                            int* __restrict__ cursor, int* __restrict__ csr_col) {
    int e = blockIdx.x * 256 + threadIdx.x;
    if (e >= E) return;
    int r = ei[e];          // destination
    int c = ei[E + e];      // source
    int pos = atomicAdd(&cursor[r], 1);
    csr_col[pos] = c;
}

// -------- GEMM: t16[N][128] = fp16(A[N][128] @ W[128][128]) ----------

__global__ __launch_bounds__(256) void gemm_nk128(const float* __restrict__ A,
                                                  const float* __restrict__ W,
                                                  _Float16* __restrict__ out, int N) {
    __shared__ float sA[32][64];     // A-tile transposed: sA[k][r]
    __shared__ float sW[32][128];
    const int t = threadIdx.x;
    const int tc = t & 15, tr = t >> 4;
    const int brow = blockIdx.x * 64;
    float acc[4][8];
#pragma unroll
    for (int r = 0; r < 4; ++r)
#pragma unroll
        for (int c = 0; c < 8; ++c) acc[r][c] = 0.0f;

    for (int kt = 0; kt < 128; kt += 32) {
#pragma unroll
        for (int i = 0; i < 2; ++i) {
            int idx = t + i * 256;          // 0..511
            int r = idx & 63, kq = idx >> 6;   // kq 0..7 -> k = kq*4
            int g = brow + r;
            float4 v = make_float4(0.f, 0.f, 0.f, 0.f);
            if (g < N) v = *(const float4*)&A[(size_t)g * 128 + kt + kq * 4];
            sA[kq * 4 + 0][r] = v.x; sA[kq * 4 + 1][r] = v.y;
            sA[kq * 4 + 2][r] = v.z; sA[kq * 4 + 3][r] = v.w;
        }
#pragma unroll
        for (int i = 0; i < 4; ++i) {
            int idx = t + i * 256;          // 0..1023
            int k = idx >> 5, cq = idx & 31;
            *(float4*)&sW[k][cq * 4] = *(const float4*)&W[(size_t)(kt + k) * 128 + cq * 4];
        }
        __syncthreads();
#pragma unroll
        for (int k = 0; k < 32; ++k) {
            float4 a  = *(const float4*)&sA[k][tr * 4];
            float4 b0 = *(const float4*)&sW[k][tc * 4];
            float4 b1 = *(const float4*)&sW[k][tc * 4 + 64];
            float ar[4] = {a.x, a.y, a.z, a.w};
            float bc[8] = {b0.x, b0.y, b0.z, b0.w, b1.x, b1.y, b1.z, b1.w};
#pragma unroll
            for (int r = 0; r < 4; ++r)
#pragma unroll
                for (int c = 0; c < 8; ++c)
                    acc[r][c] = fmaf(ar[r], bc[c], acc[r][c]);
        }
        __syncthreads();
    }
#pragma unroll
    for (int r = 0; r < 4; ++r) {
        int g = brow + tr * 4 + r;
        if (g < N) {
            half4 o0 = {(_Float16)acc[r][0], (_Float16)acc[r][1],
                        (_Float16)acc[r][2], (_Float16)acc[r][3]};
            half4 o1 = {(_Float16)acc[r][4], (_Float16)acc[r][5],
                        (_Float16)acc[r][6], (_Float16)acc[r][7]};
            *(half4*)&out[(size_t)g * 128 + tc * 4] = o0;
            *(half4*)&out[(size_t)g * 128 + tc * 4 + 64] = o1;
        }
    }
}

// ---------------- GEMM: out[N][16] = A[N][128] @ W[128][16] ----------------

__global__ __launch_bounds__(256) void gemm_nk16(const float* __restrict__ A,
                                                 const float* __restrict__ W,
                                                 float* __restrict__ out, int N) {
    __shared__ float sW[128][16];    // 8 KB
    __shared__ float sA[32][132];    // padded, 16.5 KB
    int t = threadIdx.x;
#pragma unroll
    for (int i = 0; i < 2; ++i) {
        int idx = t + i * 256;       // 0..511 float4s over 2048 floats
        *(float4*)&sW[idx >> 2][(idx & 3) * 4] = *(const float4*)&W[idx * 4];
    }
    int brow = blockIdx.x * 32;
#pragma unroll
    for (int i = 0; i < 4; ++i) {
        int idx = t + i * 256;       // 0..1023
        int rr = idx >> 5, cq = idx & 31;
        int g = brow + rr;
        float4 v = make_float4(0.f, 0.f, 0.f, 0.f);
        if (g < N) v = *(const float4*)&A[(size_t)g * 128 + cq * 4];
        *(float4*)&sA[rr][cq * 4] = v;
    }
    __syncthreads();
    int r = t >> 3;       // 0..31
    int cg = t & 7;       // cols cg*2, cg*2+1
    float a0 = 0.f, a1 = 0.f;
#pragma unroll
    for (int k = 0; k < 128; ++k) {
        float a = sA[r][k];
        float2 w = *(const float2*)&sW[k][cg * 2];
        a0 = fmaf(a, w.x, a0);
        a1 = fmaf(a, w.y, a1);
    }
    int g = brow + r;
    if (g < N) {
        out[(size_t)g * 16 + cg * 2 + 0] = a0;
        out[(size_t)g * 16 + cg * 2 + 1] = a1;
    }
}

// ----- aggregation (128 wide) from fp16 table: one node per wave, 2 edges/VMEM -----
// Wave split into two 32-lane halves; each half gathers a different edge's full
// 256B fp16 row (8B/lane). Accumulate fp32; cross-half shfl_xor(32) combine.

__global__ __launch_bounds__(256) void agg128_kernel(const _Float16* __restrict__ t,
        const int* __restrict__ csr_col,
        const int* __restrict__ offset, const float* __restrict__ dis,
        const float* __restrict__ bias, float* __restrict__ out, int N, int do_relu) {
    int node = blockIdx.x * 4 + (threadIdx.x >> 6);
    if (node >= N) return;
    int lane = threadIdx.x & 63;
    int half = lane >> 5;
    int col4 = (lane & 31) * 4;          // element index of this lane's 4 columns
    float dn = dis[node];

    // self loop (weight dn^2), accumulated by half 0 only
    half4 sv = *(const half4*)&t[(size_t)node * 128 + col4];
    float sw = half ? 0.0f : dn * dn;
    float4 acc;
    acc.x = sw * (float)sv.x; acc.y = sw * (float)sv.y;
    acc.z = sw * (float)sv.z; acc.w = sw * (float)sv.w;

    int s = offset[node], e = offset[node + 1];
    int j = s + half;                    // half 0: s, s+2, ... ; half 1: s+1, s+3, ...
    for (; j + 6 < e; j += 8) {          // 8 edges per wave in flight
        int c0 = csr_col[j];
        int c1 = csr_col[j + 2];
        int c2 = csr_col[j + 4];
        int c3 = csr_col[j + 6];
        half4 v0 = *(const half4*)&t[(size_t)c0 * 128 + col4];
        half4 v1 = *(const half4*)&t[(size_t)c1 * 128 + col4];
        half4 v2 = *(const half4*)&t[(size_t)c2 * 128 + col4];
        half4 v3 = *(const half4*)&t[(size_t)c3 * 128 + col4];
        float w0 = dn * dis[c0];
        float w1 = dn * dis[c1];
        float w2 = dn * dis[c2];
        float w3 = dn * dis[c3];
        acc.x = fmaf(w0, (float)v0.x, acc.x); acc.y = fmaf(w0, (float)v0.y, acc.y);
        acc.z = fmaf(w0, (float)v0.z, acc.z); acc.w = fmaf(w0, (float)v0.w, acc.w);
        acc.x = fmaf(w1, (float)v1.x, acc.x); acc.y = fmaf(w1, (float)v1.y, acc.y);
        acc.z = fmaf(w1, (float)v1.z, acc.z); acc.w = fmaf(w1, (float)v1.w, acc.w);
        acc.x = fmaf(w2, (float)v2.x, acc.x); acc.y = fmaf(w2, (float)v2.y, acc.y);
        acc.z = fmaf(w2, (float)v2.z, acc.z); acc.w = fmaf(w2, (float)v2.w, acc.w);
        acc.x = fmaf(w3, (float)v3.x, acc.x); acc.y = fmaf(w3, (float)v3.y, acc.y);
        acc.z = fmaf(w3, (float)v3.z, acc.z); acc.w = fmaf(w3, (float)v3.w, acc.w);
    }
    for (; j < e; j += 2) {
        int c = csr_col[j];
        half4 v = *(const half4*)&t[(size_t)c * 128 + col4];
        float w = dn * dis[c];
        acc.x = fmaf(w, (float)v.x, acc.x); acc.y = fmaf(w, (float)v.y, acc.y);
        acc.z = fmaf(w, (float)v.z, acc.z); acc.w = fmaf(w, (float)v.w, acc.w);
    }
    // combine the two halves
    acc.x += __shfl_xor(acc.x, 32);
    acc.y += __shfl_xor(acc.y, 32);
    acc.z += __shfl_xor(acc.z, 32);
    acc.w += __shfl_xor(acc.w, 32);
    if (half == 0) {
        float4 b = *(const float4*)&bias[col4];
        float4 o;
        o.x = acc.x + b.x; o.y = acc.y + b.y; o.z = acc.z + b.z; o.w = acc.w + b.w;
        if (do_relu) {
            o.x = fmaxf(o.x, 0.f); o.y = fmaxf(o.y, 0.f);
            o.z = fmaxf(o.z, 0.f); o.w = fmaxf(o.w, 0.f);
        }
        *(float4*)&out[(size_t)node * 128 + col4] = o;
    }
}

// ------- aggregation (16 wide) + bias + log_softmax: 16 lanes per node -------

__global__ __launch_bounds__(256) void agg16_ls_kernel(const float* __restrict__ t2,
        const int* __restrict__ csr_col,
        const int* __restrict__ offset, const float* __restrict__ dis,
        const float* __restrict__ b2, float* __restrict__ out, int N) {
    int gid = blockIdx.x * 256 + threadIdx.x;
    int node = gid >> 4;
    int c = gid & 15;
    if (node >= N) return;
    float dn = dis[node];
    float acc = dn * dn * t2[(size_t)node * 16 + c];
    int s = offset[node], e = offset[node + 1];
    for (int j = s; j < e; ++j) {
        int col = csr_col[j];
        float w = dn * dis[col];
        acc = fmaf(w, t2[(size_t)col * 16 + c], acc);
    }
    float v = acc + b2[c];
    float m = v;
#pragma unroll
    for (int o = 1; o < 16; o <<= 1) m = fmaxf(m, __shfl_xor(m, o, 16));
    float ex = expf(v - m);
    float ssum = ex;
#pragma unroll
    for (int o = 1; o < 16; o <<= 1) ssum += __shfl_xor(ssum, o, 16);
    out[(size_t)node * 16 + c] = v - m - logf(ssum);
}

// ---------------------------------- launch ----------------------------------

extern "C" void kernel_launch(void* const* d_in, const int* in_sizes, int n_in,
                              void* d_out, int out_size, void* d_ws, size_t ws_size,
                              hipStream_t stream) {
    const float* x  = (const float*)d_in[0];
    const int*   ei = (const int*)d_in[1];
    const float* W0 = (const float*)d_in[2];
    const float* b0 = (const float*)d_in[3];
    const float* W1 = (const float*)d_in[4];
    const float* b1 = (const float*)d_in[5];
    const float* W2 = (const float*)d_in[6];
    const float* b2 = (const float*)d_in[7];
    int N = in_sizes[0] / 128;
    int E = in_sizes[1] / 2;
    float* out = (float*)d_out;

    char* ws = (char*)d_ws;
    size_t off = 0;
    auto alloc = [&](size_t bytes) -> void* {
        void* p = ws + off;
        off = (off + bytes + 255) & ~(size_t)255;
        return p;
    };
    _Float16* t16   = (_Float16*)alloc((size_t)N * 128 * 2);
    float* tB      = (float*)alloc((size_t)N * 128 * 4);
    float* t2      = (float*)alloc((size_t)N * 16 * 4);
    int*   cnt     = (int*)alloc((size_t)N * 4);
    int*   offs    = (int*)alloc((size_t)(N + 1) * 4);
    int*   cursor  = (int*)alloc((size_t)N * 4);
    int*   blksum  = (int*)alloc(64 * 4);
    float* dis     = (float*)alloc((size_t)N * 4);
    int*   csr_col = (int*)alloc((size_t)E * 4);

    hipMemsetAsync(cnt, 0, (size_t)N * 4, stream);

    int nb = (N + 1023) / 1024;   // 49 for N=50000 (must be <= 64)
    count_kernel<<<(E + 255) / 256, 256, 0, stream>>>(ei, cnt, E);
    scan1_kernel<<<nb, 256, 0, stream>>>(cnt, offs, blksum, dis, N);
    scan2_kernel<<<1, 64, 0, stream>>>(blksum, nb);
    scan3_kernel<<<(N + 255) / 256, 256, 0, stream>>>(offs, cursor, blksum, N, E);
    fill_kernel<<<(E + 255) / 256, 256, 0, stream>>>(ei, E, cursor, csr_col);

    int gemm_blocks = (N + 63) / 64;
    int agg_blocks  = (N + 3) / 4;

    gemm_nk128<<<gemm_blocks, 256, 0, stream>>>(x, W0, t16, N);
    agg128_kernel<<<agg_blocks, 256, 0, stream>>>(t16, csr_col, offs, dis, b0, tB, N, 1);
    gemm_nk128<<<gemm_blocks, 256, 0, stream>>>(tB, W1, t16, N);
    agg128_kernel<<<agg_blocks, 256, 0, stream>>>(t16, csr_col, offs, dis, b1, tB, N, 1);
    gemm_nk16<<<(N + 31) / 32, 256, 0, stream>>>(tB, W2, t2, N);
    agg16_ls_kernel<<<(int)(((size_t)N * 16 + 255) / 256), 256, 0, stream>>>(
        t2, csr_col, offs, dis, b2, out, N);
}

// Round 5
// 254.825 us; speedup vs baseline: 1.9831x; 1.0471x over previous
//
#include <hip/hip_runtime.h>
#include <math.h>

typedef _Float16 half4 __attribute__((ext_vector_type(4)));

// ---------------- setup kernels: degree, rsqrt, scan, CSR fill ----------------

// Privatized degree histogram: copy = blockIdx&7 -> one copy per XCD under
// round-robin dispatch, so atomics stay in the local L2 (no cross-XCD ping-pong).
__global__ void count_kernel(const int* __restrict__ ei, int* __restrict__ cnt8,
                             int N, int E) {
    int e = blockIdx.x * 256 + threadIdx.x;
    int copy = blockIdx.x & 7;
    if (e < E) atomicAdd(&cnt8[(size_t)copy * N + ei[e]], 1);
}

// exclusive scan of deg[N] -> excl[N]; sums the 8 histogram copies and
// computes dis = rsqrt(deg+1)
__global__ void scan1_kernel(const int* __restrict__ cnt8, int* __restrict__ excl,
                             int* __restrict__ blksum, float* __restrict__ dis,
                             int N) {
    __shared__ int sdata[256];
    int t = threadIdx.x;
    int base = blockIdx.x * 1024 + t * 4;
    int v0 = 0, v1 = 0, v2 = 0, v3 = 0;
#pragma unroll
    for (int k = 0; k < 8; ++k) {
        const int* c = cnt8 + (size_t)k * N;
        if (base + 0 < N) v0 += c[base + 0];
        if (base + 1 < N) v1 += c[base + 1];
        if (base + 2 < N) v2 += c[base + 2];
        if (base + 3 < N) v3 += c[base + 3];
    }
    if (base + 0 < N) dis[base + 0] = rsqrtf((float)v0 + 1.0f);
    if (base + 1 < N) dis[base + 1] = rsqrtf((float)v1 + 1.0f);
    if (base + 2 < N) dis[base + 2] = rsqrtf((float)v2 + 1.0f);
    if (base + 3 < N) dis[base + 3] = rsqrtf((float)v3 + 1.0f);
    int tot = v0 + v1 + v2 + v3;
    sdata[t] = tot;
    __syncthreads();
    for (int o = 1; o < 256; o <<= 1) {
        int x = (t >= o) ? sdata[t - o] : 0;
        __syncthreads();
        sdata[t] += x;
        __syncthreads();
    }
    int incl = sdata[t];
    int eb = incl - tot;
    if (base + 0 < N) excl[base + 0] = eb;
    if (base + 1 < N) excl[base + 1] = eb + v0;
    if (base + 2 < N) excl[base + 2] = eb + v0 + v1;
    if (base + 3 < N) excl[base + 3] = eb + v0 + v1 + v2;
    if (t == 255) blksum[blockIdx.x] = incl;
}

__global__ void scan2_kernel(int* __restrict__ blksum, int nb) {  // 1 block, 64 threads
    int lane = threadIdx.x;
    int orig = (lane < nb) ? blksum[lane] : 0;
    int v = orig;
    for (int o = 1; o < 64; o <<= 1) { int x = __shfl_up(v, o); if (lane >= o) v += x; }
    if (lane < nb) blksum[lane] = v - orig;   // exclusive block base
}

__global__ void scan3_kernel(int* __restrict__ excl, int* __restrict__ cursor,
                             const int* __restrict__ blksum, int N, int E) {
    int i = blockIdx.x * 256 + threadIdx.x;
    if (i < N) {
        int v = excl[i] + blksum[i >> 10];
        excl[i] = v;
        cursor[i] = v;      // cursor starts at row offset -> fill atomic gives abs pos
    }
    if (i == 0) excl[N] = E;
}

// XCD-partitioned CSR fill: 8 blocks per 256-edge chunk; block's partition
// part = blockIdx&7 owns dest range [part*PART, (part+1)*PART). All cursor
// atomics and csr_col stores then hit an XCD-local L2 region -> no cross-XCD
// line ping-pong (the cause of R4's 16x write amplification).
__global__ void fill_kernel(const int* __restrict__ ei, int E, int PART,
                            int* __restrict__ cursor, int* __restrict__ csr_col) {
    int part = blockIdx.x & 7;
    int e = (blockIdx.x >> 3) * 256 + threadIdx.x;
    if (e >= E) return;
    int r = ei[e];          // destination
    int lo = part * PART;
    if (r < lo || r >= lo + PART) return;
    int c = ei[E + e];      // source
    int pos = atomicAdd(&cursor[r], 1);
    csr_col[pos] = c;
}

// -------- GEMM: t16[N][128] = fp16(A[N][128] @ W[128][128]) ----------

__global__ __launch_bounds__(256) void gemm_nk128(const float* __restrict__ A,
                                                  const float* __restrict__ W,
                                                  _Float16* __restrict__ out, int N) {
    __shared__ float sA[32][64];     // A-tile transposed: sA[k][r]
    __shared__ float sW[32][128];
    const int t = threadIdx.x;
    const int tc = t & 15, tr = t >> 4;
    const int brow = blockIdx.x * 64;
    float acc[4][8];
#pragma unroll
    for (int r = 0; r < 4; ++r)
#pragma unroll
        for (int c = 0; c < 8; ++c) acc[r][c] = 0.0f;

    for (int kt = 0; kt < 128; kt += 32) {
#pragma unroll
        for (int i = 0; i < 2; ++i) {
            int idx = t + i * 256;          // 0..511
            int r = idx & 63, kq = idx >> 6;   // kq 0..7 -> k = kq*4
            int g = brow + r;
            float4 v = make_float4(0.f, 0.f, 0.f, 0.f);
            if (g < N) v = *(const float4*)&A[(size_t)g * 128 + kt + kq * 4];
            sA[kq * 4 + 0][r] = v.x; sA[kq * 4 + 1][r] = v.y;
            sA[kq * 4 + 2][r] = v.z; sA[kq * 4 + 3][r] = v.w;
        }
#pragma unroll
        for (int i = 0; i < 4; ++i) {
            int idx = t + i * 256;          // 0..1023
            int k = idx >> 5, cq = idx & 31;
            *(float4*)&sW[k][cq * 4] = *(const float4*)&W[(size_t)(kt + k) * 128 + cq * 4];
        }
        __syncthreads();
#pragma unroll
        for (int k = 0; k < 32; ++k) {
            float4 a  = *(const float4*)&sA[k][tr * 4];
            float4 b0 = *(const float4*)&sW[k][tc * 4];
            float4 b1 = *(const float4*)&sW[k][tc * 4 + 64];
            float ar[4] = {a.x, a.y, a.z, a.w};
            float bc[8] = {b0.x, b0.y, b0.z, b0.w, b1.x, b1.y, b1.z, b1.w};
#pragma unroll
            for (int r = 0; r < 4; ++r)
#pragma unroll
                for (int c = 0; c < 8; ++c)
                    acc[r][c] = fmaf(ar[r], bc[c], acc[r][c]);
        }
        __syncthreads();
    }
#pragma unroll
    for (int r = 0; r < 4; ++r) {
        int g = brow + tr * 4 + r;
        if (g < N) {
            half4 o0 = {(_Float16)acc[r][0], (_Float16)acc[r][1],
                        (_Float16)acc[r][2], (_Float16)acc[r][3]};
            half4 o1 = {(_Float16)acc[r][4], (_Float16)acc[r][5],
                        (_Float16)acc[r][6], (_Float16)acc[r][7]};
            *(half4*)&out[(size_t)g * 128 + tc * 4] = o0;
            *(half4*)&out[(size_t)g * 128 + tc * 4 + 64] = o1;
        }
    }
}

// ---------------- GEMM: out[N][16] = A[N][128] @ W[128][16] ----------------

__global__ __launch_bounds__(256) void gemm_nk16(const float* __restrict__ A,
                                                 const float* __restrict__ W,
                                                 float* __restrict__ out, int N) {
    __shared__ float sW[128][16];    // 8 KB
    __shared__ float sA[32][132];    // padded, 16.5 KB
    int t = threadIdx.x;
#pragma unroll
    for (int i = 0; i < 2; ++i) {
        int idx = t + i * 256;       // 0..511 float4s over 2048 floats
        *(float4*)&sW[idx >> 2][(idx & 3) * 4] = *(const float4*)&W[idx * 4];
    }
    int brow = blockIdx.x * 32;
#pragma unroll
    for (int i = 0; i < 4; ++i) {
        int idx = t + i * 256;       // 0..1023
        int rr = idx >> 5, cq = idx & 31;
        int g = brow + rr;
        float4 v = make_float4(0.f, 0.f, 0.f, 0.f);
        if (g < N) v = *(const float4*)&A[(size_t)g * 128 + cq * 4];
        *(float4*)&sA[rr][cq * 4] = v;
    }
    __syncthreads();
    int r = t >> 3;       // 0..31
    int cg = t & 7;       // cols cg*2, cg*2+1
    float a0 = 0.f, a1 = 0.f;
#pragma unroll
    for (int k = 0; k < 128; ++k) {
        float a = sA[r][k];
        float2 w = *(const float2*)&sW[k][cg * 2];
        a0 = fmaf(a, w.x, a0);
        a1 = fmaf(a, w.y, a1);
    }
    int g = brow + r;
    if (g < N) {
        out[(size_t)g * 16 + cg * 2 + 0] = a0;
        out[(size_t)g * 16 + cg * 2 + 1] = a1;
    }
}

// ----- aggregation (128 wide) from fp16 table: one node per wave, 2 edges/VMEM -----

__global__ __launch_bounds__(256) void agg128_kernel(const _Float16* __restrict__ t,
        const int* __restrict__ csr_col,
        const int* __restrict__ offset, const float* __restrict__ dis,
        const float* __restrict__ bias, float* __restrict__ out, int N, int do_relu) {
    int node = blockIdx.x * 4 + (threadIdx.x >> 6);
    if (node >= N) return;
    int lane = threadIdx.x & 63;
    int half = lane >> 5;
    int col4 = (lane & 31) * 4;          // element index of this lane's 4 columns
    float dn = dis[node];

    // self loop (weight dn^2), accumulated by half 0 only
    half4 sv = *(const half4*)&t[(size_t)node * 128 + col4];
    float sw = half ? 0.0f : dn * dn;
    float4 acc;
    acc.x = sw * (float)sv.x; acc.y = sw * (float)sv.y;
    acc.z = sw * (float)sv.z; acc.w = sw * (float)sv.w;

    int s = offset[node], e = offset[node + 1];
    int j = s + half;                    // half 0: s, s+2, ... ; half 1: s+1, s+3, ...
    for (; j + 6 < e; j += 8) {          // 8 edges per wave in flight
        int c0 = csr_col[j];
        int c1 = csr_col[j + 2];
        int c2 = csr_col[j + 4];
        int c3 = csr_col[j + 6];
        half4 v0 = *(const half4*)&t[(size_t)c0 * 128 + col4];
        half4 v1 = *(const half4*)&t[(size_t)c1 * 128 + col4];
        half4 v2 = *(const half4*)&t[(size_t)c2 * 128 + col4];
        half4 v3 = *(const half4*)&t[(size_t)c3 * 128 + col4];
        float w0 = dn * dis[c0];
        float w1 = dn * dis[c1];
        float w2 = dn * dis[c2];
        float w3 = dn * dis[c3];
        acc.x = fmaf(w0, (float)v0.x, acc.x); acc.y = fmaf(w0, (float)v0.y, acc.y);
        acc.z = fmaf(w0, (float)v0.z, acc.z); acc.w = fmaf(w0, (float)v0.w, acc.w);
        acc.x = fmaf(w1, (float)v1.x, acc.x); acc.y = fmaf(w1, (float)v1.y, acc.y);
        acc.z = fmaf(w1, (float)v1.z, acc.z); acc.w = fmaf(w1, (float)v1.w, acc.w);
        acc.x = fmaf(w2, (float)v2.x, acc.x); acc.y = fmaf(w2, (float)v2.y, acc.y);
        acc.z = fmaf(w2, (float)v2.z, acc.z); acc.w = fmaf(w2, (float)v2.w, acc.w);
        acc.x = fmaf(w3, (float)v3.x, acc.x); acc.y = fmaf(w3, (float)v3.y, acc.y);
        acc.z = fmaf(w3, (float)v3.z, acc.z); acc.w = fmaf(w3, (float)v3.w, acc.w);
    }
    for (; j < e; j += 2) {
        int c = csr_col[j];
        half4 v = *(const half4*)&t[(size_t)c * 128 + col4];
        float w = dn * dis[c];
        acc.x = fmaf(w, (float)v.x, acc.x); acc.y = fmaf(w, (float)v.y, acc.y);
        acc.z = fmaf(w, (float)v.z, acc.z); acc.w = fmaf(w, (float)v.w, acc.w);
    }
    // combine the two halves
    acc.x += __shfl_xor(acc.x, 32);
    acc.y += __shfl_xor(acc.y, 32);
    acc.z += __shfl_xor(acc.z, 32);
    acc.w += __shfl_xor(acc.w, 32);
    if (half == 0) {
        float4 b = *(const float4*)&bias[col4];
        float4 o;
        o.x = acc.x + b.x; o.y = acc.y + b.y; o.z = acc.z + b.z; o.w = acc.w + b.w;
        if (do_relu) {
            o.x = fmaxf(o.x, 0.f); o.y = fmaxf(o.y, 0.f);
            o.z = fmaxf(o.z, 0.f); o.w = fmaxf(o.w, 0.f);
        }
        *(float4*)&out[(size_t)node * 128 + col4] = o;
    }
}

// ------- aggregation (16 wide) + bias + log_softmax: 16 lanes per node -------

__global__ __launch_bounds__(256) void agg16_ls_kernel(const float* __restrict__ t2,
        const int* __restrict__ csr_col,
        const int* __restrict__ offset, const float* __restrict__ dis,
        const float* __restrict__ b2, float* __restrict__ out, int N) {
    int gid = blockIdx.x * 256 + threadIdx.x;
    int node = gid >> 4;
    int c = gid & 15;
    if (node >= N) return;
    float dn = dis[node];
    float acc = dn * dn * t2[(size_t)node * 16 + c];
    int s = offset[node], e = offset[node + 1];
    for (int j = s; j < e; ++j) {
        int col = csr_col[j];
        float w = dn * dis[col];
        acc = fmaf(w, t2[(size_t)col * 16 + c], acc);
    }
    float v = acc + b2[c];
    float m = v;
#pragma unroll
    for (int o = 1; o < 16; o <<= 1) m = fmaxf(m, __shfl_xor(m, o, 16));
    float ex = expf(v - m);
    float ssum = ex;
#pragma unroll
    for (int o = 1; o < 16; o <<= 1) ssum += __shfl_xor(ssum, o, 16);
    out[(size_t)node * 16 + c] = v - m - logf(ssum);
}

// ---------------------------------- launch ----------------------------------

extern "C" void kernel_launch(void* const* d_in, const int* in_sizes, int n_in,
                              void* d_out, int out_size, void* d_ws, size_t ws_size,
                              hipStream_t stream) {
    const float* x  = (const float*)d_in[0];
    const int*   ei = (const int*)d_in[1];
    const float* W0 = (const float*)d_in[2];
    const float* b0 = (const float*)d_in[3];
    const float* W1 = (const float*)d_in[4];
    const float* b1 = (const float*)d_in[5];
    const float* W2 = (const float*)d_in[6];
    const float* b2 = (const float*)d_in[7];
    int N = in_sizes[0] / 128;
    int E = in_sizes[1] / 2;
    int PART = (N + 7) / 8;
    float* out = (float*)d_out;

    char* ws = (char*)d_ws;
    size_t off = 0;
    auto alloc = [&](size_t bytes) -> void* {
        void* p = ws + off;
        off = (off + bytes + 255) & ~(size_t)255;
        return p;
    };
    _Float16* t16  = (_Float16*)alloc((size_t)N * 128 * 2);
    float* tB      = (float*)alloc((size_t)N * 128 * 4);
    float* t2      = (float*)alloc((size_t)N * 16 * 4);
    int*   cnt8    = (int*)alloc((size_t)N * 8 * 4);
    int*   offs    = (int*)alloc((size_t)(N + 1) * 4);
    int*   cursor  = (int*)alloc((size_t)N * 4);
    int*   blksum  = (int*)alloc(64 * 4);
    float* dis     = (float*)alloc((size_t)N * 4);
    int*   csr_col = (int*)alloc((size_t)E * 4);

    hipMemsetAsync(cnt8, 0, (size_t)N * 8 * 4, stream);

    int nchunk = (E + 255) / 256;
    int nb = (N + 1023) / 1024;   // 49 for N=50000 (must be <= 64)
    count_kernel<<<nchunk, 256, 0, stream>>>(ei, cnt8, N, E);
    scan1_kernel<<<nb, 256, 0, stream>>>(cnt8, offs, blksum, dis, N);
    scan2_kernel<<<1, 64, 0, stream>>>(blksum, nb);
    scan3_kernel<<<(N + 255) / 256, 256, 0, stream>>>(offs, cursor, blksum, N, E);
    fill_kernel<<<nchunk * 8, 256, 0, stream>>>(ei, E, PART, cursor, csr_col);

    int gemm_blocks = (N + 63) / 64;
    int agg_blocks  = (N + 3) / 4;

    gemm_nk128<<<gemm_blocks, 256, 0, stream>>>(x, W0, t16, N);
    agg128_kernel<<<agg_blocks, 256, 0, stream>>>(t16, csr_col, offs, dis, b0, tB, N, 1);
    gemm_nk128<<<gemm_blocks, 256, 0, stream>>>(tB, W1, t16, N);
    agg128_kernel<<<agg_blocks, 256, 0, stream>>>(t16, csr_col, offs, dis, b1, tB, N, 1);
    gemm_nk16<<<(N + 31) / 32, 256, 0, stream>>>(tB, W2, t2, N);
    agg16_ls_kernel<<<(int)(((size_t)N * 16 + 255) / 256), 256, 0, stream>>>(
        t2, csr_col, offs, dis, b2, out, N);
}

// Round 6
// 254.793 us; speedup vs baseline: 1.9834x; 1.0001x over previous
//
#include <hip/hip_runtime.h>
#include <math.h>

typedef _Float16 half4 __attribute__((ext_vector_type(4)));

// ---------------- setup kernels: degree, rsqrt, scan, CSR fill ----------------

// grid-stride int4 zero fill (replaces rocclr fillBuffer, which launches a
// tiny latency-bound grid: 40us for 1.6MB L2-resident -> ~2us here)
__global__ void zero_kernel(int4* __restrict__ p, int n4) {
    int i = blockIdx.x * 256 + threadIdx.x;
    int stride = gridDim.x * 256;
    for (; i < n4; i += stride) p[i] = make_int4(0, 0, 0, 0);
}

// Privatized degree histogram: copy = blockIdx&7 -> one copy per XCD under
// round-robin dispatch, so atomics stay in the local L2 (no cross-XCD ping-pong).
__global__ void count_kernel(const int* __restrict__ ei, int* __restrict__ cnt8,
                             int N, int E) {
    int e = blockIdx.x * 256 + threadIdx.x;
    int copy = blockIdx.x & 7;
    if (e < E) atomicAdd(&cnt8[(size_t)copy * N + ei[e]], 1);
}

// exclusive scan of deg[N] -> excl[N]; sums the 8 histogram copies and
// computes dis = rsqrt(deg+1)
__global__ void scan1_kernel(const int* __restrict__ cnt8, int* __restrict__ excl,
                             int* __restrict__ blksum, float* __restrict__ dis,
                             int N) {
    __shared__ int sdata[256];
    int t = threadIdx.x;
    int base = blockIdx.x * 1024 + t * 4;
    int v0 = 0, v1 = 0, v2 = 0, v3 = 0;
#pragma unroll
    for (int k = 0; k < 8; ++k) {
        const int* c = cnt8 + (size_t)k * N;
        if (base + 0 < N) v0 += c[base + 0];
        if (base + 1 < N) v1 += c[base + 1];
        if (base + 2 < N) v2 += c[base + 2];
        if (base + 3 < N) v3 += c[base + 3];
    }
    if (base + 0 < N) dis[base + 0] = rsqrtf((float)v0 + 1.0f);
    if (base + 1 < N) dis[base + 1] = rsqrtf((float)v1 + 1.0f);
    if (base + 2 < N) dis[base + 2] = rsqrtf((float)v2 + 1.0f);
    if (base + 3 < N) dis[base + 3] = rsqrtf((float)v3 + 1.0f);
    int tot = v0 + v1 + v2 + v3;
    sdata[t] = tot;
    __syncthreads();
    for (int o = 1; o < 256; o <<= 1) {
        int x = (t >= o) ? sdata[t - o] : 0;
        __syncthreads();
        sdata[t] += x;
        __syncthreads();
    }
    int incl = sdata[t];
    int eb = incl - tot;
    if (base + 0 < N) excl[base + 0] = eb;
    if (base + 1 < N) excl[base + 1] = eb + v0;
    if (base + 2 < N) excl[base + 2] = eb + v0 + v1;
    if (base + 3 < N) excl[base + 3] = eb + v0 + v1 + v2;
    if (t == 255) blksum[blockIdx.x] = incl;
}

__global__ void scan2_kernel(int* __restrict__ blksum, int nb) {  // 1 block, 64 threads
    int lane = threadIdx.x;
    int orig = (lane < nb) ? blksum[lane] : 0;
    int v = orig;
    for (int o = 1; o < 64; o <<= 1) { int x = __shfl_up(v, o); if (lane >= o) v += x; }
    if (lane < nb) blksum[lane] = v - orig;   // exclusive block base
}

__global__ void scan3_kernel(int* __restrict__ excl, int* __restrict__ cursor,
                             const int* __restrict__ blksum, int N, int E) {
    int i = blockIdx.x * 256 + threadIdx.x;
    if (i < N) {
        int v = excl[i] + blksum[i >> 10];
        excl[i] = v;
        cursor[i] = v;      // cursor starts at row offset -> fill atomic gives abs pos
    }
    if (i == 0) excl[N] = E;
}

// XCD-partitioned CSR fill: 8 blocks per 256-edge chunk; block's partition
// part = blockIdx&7 owns dest range [part*PART, (part+1)*PART). All cursor
// atomics and csr_col stores then hit an XCD-local L2 region -> no cross-XCD
// line ping-pong (the cause of R4's 16x write amplification).
__global__ void fill_kernel(const int* __restrict__ ei, int E, int PART,
                            int* __restrict__ cursor, int* __restrict__ csr_col) {
    int part = blockIdx.x & 7;
    int e = (blockIdx.x >> 3) * 256 + threadIdx.x;
    if (e >= E) return;
    int r = ei[e];          // destination
    int lo = part * PART;
    if (r < lo || r >= lo + PART) return;
    int c = ei[E + e];      // source
    int pos = atomicAdd(&cursor[r], 1);
    csr_col[pos] = c;
}

// -------- GEMM: t16[N][128] = fp16(A[N][128] @ W[128][128]) ----------

__global__ __launch_bounds__(256) void gemm_nk128(const float* __restrict__ A,
                                                  const float* __restrict__ W,
                                                  _Float16* __restrict__ out, int N) {
    __shared__ float sA[32][64];     // A-tile transposed: sA[k][r]
    __shared__ float sW[32][128];
    const int t = threadIdx.x;
    const int tc = t & 15, tr = t >> 4;
    const int brow = blockIdx.x * 64;
    float acc[4][8];
#pragma unroll
    for (int r = 0; r < 4; ++r)
#pragma unroll
        for (int c = 0; c < 8; ++c) acc[r][c] = 0.0f;

    for (int kt = 0; kt < 128; kt += 32) {
#pragma unroll
        for (int i = 0; i < 2; ++i) {
            int idx = t + i * 256;          // 0..511
            int r = idx & 63, kq = idx >> 6;   // kq 0..7 -> k = kq*4
            int g = brow + r;
            float4 v = make_float4(0.f, 0.f, 0.f, 0.f);
            if (g < N) v = *(const float4*)&A[(size_t)g * 128 + kt + kq * 4];
            sA[kq * 4 + 0][r] = v.x; sA[kq * 4 + 1][r] = v.y;
            sA[kq * 4 + 2][r] = v.z; sA[kq * 4 + 3][r] = v.w;
        }
#pragma unroll
        for (int i = 0; i < 4; ++i) {
            int idx = t + i * 256;          // 0..1023
            int k = idx >> 5, cq = idx & 31;
            *(float4*)&sW[k][cq * 4] = *(const float4*)&W[(size_t)(kt + k) * 128 + cq * 4];
        }
        __syncthreads();
#pragma unroll
        for (int k = 0; k < 32; ++k) {
            float4 a  = *(const float4*)&sA[k][tr * 4];
            float4 b0 = *(const float4*)&sW[k][tc * 4];
            float4 b1 = *(const float4*)&sW[k][tc * 4 + 64];
            float ar[4] = {a.x, a.y, a.z, a.w};
            float bc[8] = {b0.x, b0.y, b0.z, b0.w, b1.x, b1.y, b1.z, b1.w};
#pragma unroll
            for (int r = 0; r < 4; ++r)
#pragma unroll
                for (int c = 0; c < 8; ++c)
                    acc[r][c] = fmaf(ar[r], bc[c], acc[r][c]);
        }
        __syncthreads();
    }
#pragma unroll
    for (int r = 0; r < 4; ++r) {
        int g = brow + tr * 4 + r;
        if (g < N) {
            half4 o0 = {(_Float16)acc[r][0], (_Float16)acc[r][1],
                        (_Float16)acc[r][2], (_Float16)acc[r][3]};
            half4 o1 = {(_Float16)acc[r][4], (_Float16)acc[r][5],
                        (_Float16)acc[r][6], (_Float16)acc[r][7]};
            *(half4*)&out[(size_t)g * 128 + tc * 4] = o0;
            *(half4*)&out[(size_t)g * 128 + tc * 4 + 64] = o1;
        }
    }
}

// ---------------- GEMM: out[N][16] = A[N][128] @ W[128][16] ----------------

__global__ __launch_bounds__(256) void gemm_nk16(const float* __restrict__ A,
                                                 const float* __restrict__ W,
                                                 float* __restrict__ out, int N) {
    __shared__ float sW[128][16];    // 8 KB
    __shared__ float sA[32][132];    // padded, 16.5 KB
    int t = threadIdx.x;
#pragma unroll
    for (int i = 0; i < 2; ++i) {
        int idx = t + i * 256;       // 0..511 float4s over 2048 floats
        *(float4*)&sW[idx >> 2][(idx & 3) * 4] = *(const float4*)&W[idx * 4];
    }
    int brow = blockIdx.x * 32;
#pragma unroll
    for (int i = 0; i < 4; ++i) {
        int idx = t + i * 256;       // 0..1023
        int rr = idx >> 5, cq = idx & 31;
        int g = brow + rr;
        float4 v = make_float4(0.f, 0.f, 0.f, 0.f);
        if (g < N) v = *(const float4*)&A[(size_t)g * 128 + cq * 4];
        *(float4*)&sA[rr][cq * 4] = v;
    }
    __syncthreads();
    int r = t >> 3;       // 0..31
    int cg = t & 7;       // cols cg*2, cg*2+1
    float a0 = 0.f, a1 = 0.f;
#pragma unroll
    for (int k = 0; k < 128; ++k) {
        float a = sA[r][k];
        float2 w = *(const float2*)&sW[k][cg * 2];
        a0 = fmaf(a, w.x, a0);
        a1 = fmaf(a, w.y, a1);
    }
    int g = brow + r;
    if (g < N) {
        out[(size_t)g * 16 + cg * 2 + 0] = a0;
        out[(size_t)g * 16 + cg * 2 + 1] = a1;
    }
}

// ----- aggregation (128 wide) from fp16 table: one node per wave, 2 edges/VMEM -----

__global__ __launch_bounds__(256) void agg128_kernel(const _Float16* __restrict__ t,
        const int* __restrict__ csr_col,
        const int* __restrict__ offset, const float* __restrict__ dis,
        const float* __restrict__ bias, float* __restrict__ out, int N, int do_relu) {
    int node = blockIdx.x * 4 + (threadIdx.x >> 6);
    if (node >= N) return;
    int lane = threadIdx.x & 63;
    int half = lane >> 5;
    int col4 = (lane & 31) * 4;          // element index of this lane's 4 columns
    float dn = dis[node];

    // self loop (weight dn^2), accumulated by half 0 only
    half4 sv = *(const half4*)&t[(size_t)node * 128 + col4];
    float sw = half ? 0.0f : dn * dn;
    float4 acc;
    acc.x = sw * (float)sv.x; acc.y = sw * (float)sv.y;
    acc.z = sw * (float)sv.z; acc.w = sw * (float)sv.w;

    int s = offset[node], e = offset[node + 1];
    int j = s + half;                    // half 0: s, s+2, ... ; half 1: s+1, s+3, ...
    for (; j + 6 < e; j += 8) {          // 8 edges per wave in flight
        int c0 = csr_col[j];
        int c1 = csr_col[j + 2];
        int c2 = csr_col[j + 4];
        int c3 = csr_col[j + 6];
        half4 v0 = *(const half4*)&t[(size_t)c0 * 128 + col4];
        half4 v1 = *(const half4*)&t[(size_t)c1 * 128 + col4];
        half4 v2 = *(const half4*)&t[(size_t)c2 * 128 + col4];
        half4 v3 = *(const half4*)&t[(size_t)c3 * 128 + col4];
        float w0 = dn * dis[c0];
        float w1 = dn * dis[c1];
        float w2 = dn * dis[c2];
        float w3 = dn * dis[c3];
        acc.x = fmaf(w0, (float)v0.x, acc.x); acc.y = fmaf(w0, (float)v0.y, acc.y);
        acc.z = fmaf(w0, (float)v0.z, acc.z); acc.w = fmaf(w0, (float)v0.w, acc.w);
        acc.x = fmaf(w1, (float)v1.x, acc.x); acc.y = fmaf(w1, (float)v1.y, acc.y);
        acc.z = fmaf(w1, (float)v1.z, acc.z); acc.w = fmaf(w1, (float)v1.w, acc.w);
        acc.x = fmaf(w2, (float)v2.x, acc.x); acc.y = fmaf(w2, (float)v2.y, acc.y);
        acc.z = fmaf(w2, (float)v2.z, acc.z); acc.w = fmaf(w2, (float)v2.w, acc.w);
        acc.x = fmaf(w3, (float)v3.x, acc.x); acc.y = fmaf(w3, (float)v3.y, acc.y);
        acc.z = fmaf(w3, (float)v3.z, acc.z); acc.w = fmaf(w3, (float)v3.w, acc.w);
    }
    for (; j < e; j += 2) {
        int c = csr_col[j];
        half4 v = *(const half4*)&t[(size_t)c * 128 + col4];
        float w = dn * dis[c];
        acc.x = fmaf(w, (float)v.x, acc.x); acc.y = fmaf(w, (float)v.y, acc.y);
        acc.z = fmaf(w, (float)v.z, acc.z); acc.w = fmaf(w, (float)v.w, acc.w);
    }
    // combine the two halves
    acc.x += __shfl_xor(acc.x, 32);
    acc.y += __shfl_xor(acc.y, 32);
    acc.z += __shfl_xor(acc.z, 32);
    acc.w += __shfl_xor(acc.w, 32);
    if (half == 0) {
        float4 b = *(const float4*)&bias[col4];
        float4 o;
        o.x = acc.x + b.x; o.y = acc.y + b.y; o.z = acc.z + b.z; o.w = acc.w + b.w;
        if (do_relu) {
            o.x = fmaxf(o.x, 0.f); o.y = fmaxf(o.y, 0.f);
            o.z = fmaxf(o.z, 0.f); o.w = fmaxf(o.w, 0.f);
        }
        *(float4*)&out[(size_t)node * 128 + col4] = o;
    }
}

// ------- aggregation (16 wide) + bias + log_softmax: 16 lanes per node -------

__global__ __launch_bounds__(256) void agg16_ls_kernel(const float* __restrict__ t2,
        const int* __restrict__ csr_col,
        const int* __restrict__ offset, const float* __restrict__ dis,
        const float* __restrict__ b2, float* __restrict__ out, int N) {
    int gid = blockIdx.x * 256 + threadIdx.x;
    int node = gid >> 4;
    int c = gid & 15;
    if (node >= N) return;
    float dn = dis[node];
    float acc = dn * dn * t2[(size_t)node * 16 + c];
    int s = offset[node], e = offset[node + 1];
    for (int j = s; j < e; ++j) {
        int col = csr_col[j];
        float w = dn * dis[col];
        acc = fmaf(w, t2[(size_t)col * 16 + c], acc);
    }
    float v = acc + b2[c];
    float m = v;
#pragma unroll
    for (int o = 1; o < 16; o <<= 1) m = fmaxf(m, __shfl_xor(m, o, 16));
    float ex = expf(v - m);
    float ssum = ex;
#pragma unroll
    for (int o = 1; o < 16; o <<= 1) ssum += __shfl_xor(ssum, o, 16);
    out[(size_t)node * 16 + c] = v - m - logf(ssum);
}

// ---------------------------------- launch ----------------------------------

extern "C" void kernel_launch(void* const* d_in, const int* in_sizes, int n_in,
                              void* d_out, int out_size, void* d_ws, size_t ws_size,
                              hipStream_t stream) {
    const float* x  = (const float*)d_in[0];
    const int*   ei = (const int*)d_in[1];
    const float* W0 = (const float*)d_in[2];
    const float* b0 = (const float*)d_in[3];
    const float* W1 = (const float*)d_in[4];
    const float* b1 = (const float*)d_in[5];
    const float* W2 = (const float*)d_in[6];
    const float* b2 = (const float*)d_in[7];
    int N = in_sizes[0] / 128;
    int E = in_sizes[1] / 2;
    int PART = (N + 7) / 8;
    float* out = (float*)d_out;

    char* ws = (char*)d_ws;
    size_t off = 0;
    auto alloc = [&](size_t bytes) -> void* {
        void* p = ws + off;
        off = (off + bytes + 255) & ~(size_t)255;
        return p;
    };
    _Float16* t16  = (_Float16*)alloc((size_t)N * 128 * 2);
    float* tB      = (float*)alloc((size_t)N * 128 * 4);
    float* t2      = (float*)alloc((size_t)N * 16 * 4);
    int*   cnt8    = (int*)alloc((size_t)N * 8 * 4);
    int*   offs    = (int*)alloc((size_t)(N + 1) * 4);
    int*   cursor  = (int*)alloc((size_t)N * 4);
    int*   blksum  = (int*)alloc(64 * 4);
    float* dis     = (float*)alloc((size_t)N * 4);
    int*   csr_col = (int*)alloc((size_t)E * 4);

    int n4 = (int)(((size_t)N * 8 + 3) / 4);   // cnt8 int4 count (N*8 % 4 == 0)
    zero_kernel<<<400, 256, 0, stream>>>((int4*)cnt8, n4);

    int nchunk = (E + 255) / 256;
    int nb = (N + 1023) / 1024;   // 49 for N=50000 (must be <= 64)
    count_kernel<<<nchunk, 256, 0, stream>>>(ei, cnt8, N, E);
    scan1_kernel<<<nb, 256, 0, stream>>>(cnt8, offs, blksum, dis, N);
    scan2_kernel<<<1, 64, 0, stream>>>(blksum, nb);
    scan3_kernel<<<(N + 255) / 256, 256, 0, stream>>>(offs, cursor, blksum, N, E);
    fill_kernel<<<nchunk * 8, 256, 0, stream>>>(ei, E, PART, cursor, csr_col);

    int gemm_blocks = (N + 63) / 64;
    int agg_blocks  = (N + 3) / 4;

    gemm_nk128<<<gemm_blocks, 256, 0, stream>>>(x, W0, t16, N);
    agg128_kernel<<<agg_blocks, 256, 0, stream>>>(t16, csr_col, offs, dis, b0, tB, N, 1);
    gemm_nk128<<<gemm_blocks, 256, 0, stream>>>(tB, W1, t16, N);
    agg128_kernel<<<agg_blocks, 256, 0, stream>>>(t16, csr_col, offs, dis, b1, tB, N, 1);
    gemm_nk16<<<(N + 31) / 32, 256, 0, stream>>>(tB, W2, t2, N);
    agg16_ls_kernel<<<(int)(((size_t)N * 16 + 255) / 256), 256, 0, stream>>>(
        t2, csr_col, offs, dis, b2, out, N);
}

// Round 7
// 216.572 us; speedup vs baseline: 2.3334x; 1.1765x over previous
//
#include <hip/hip_runtime.h>
#include <math.h>

typedef _Float16 half4v __attribute__((ext_vector_type(4)));
typedef _Float16 half8v __attribute__((ext_vector_type(8)));
typedef float f32x4 __attribute__((ext_vector_type(4)));

// ------------- setup: zero cnt8 + convert/transpose W0,W1 to fp16 -------------

__global__ void setup_kernel(const float* __restrict__ W0, const float* __restrict__ W1,
                             _Float16* __restrict__ Wt0, _Float16* __restrict__ Wt1,
                             int4* __restrict__ cnt, int n4) {
    int gid = blockIdx.x * 256 + threadIdx.x;
    if (gid < 32768) {            // 2 matrices x 16384 elems: Wt[n][k] = (fp16)W[k][n]
        int m = gid >> 14;
        int rem = gid & 16383;
        int n = rem >> 7, k = rem & 127;
        const float* W = m ? W1 : W0;
        _Float16* Wt = m ? Wt1 : Wt0;
        Wt[n * 128 + k] = (_Float16)W[k * 128 + n];
    }
    int stride = gridDim.x * 256;
    for (int i = gid; i < n4; i += stride) cnt[i] = make_int4(0, 0, 0, 0);
}

// Privatized degree histogram: copy = blockIdx&7 -> XCD-local atomics.
__global__ void count_kernel(const int* __restrict__ ei, int* __restrict__ cnt8,
                             int N, int E) {
    int e = blockIdx.x * 256 + threadIdx.x;
    int copy = blockIdx.x & 7;
    if (e < E) atomicAdd(&cnt8[(size_t)copy * N + ei[e]], 1);
}

// exclusive scan of deg -> excl; sums 8 histogram copies; dis = rsqrt(deg+1)
__global__ void scan1_kernel(const int* __restrict__ cnt8, int* __restrict__ excl,
                             int* __restrict__ blksum, float* __restrict__ dis,
                             int N) {
    __shared__ int sdata[256];
    int t = threadIdx.x;
    int base = blockIdx.x * 1024 + t * 4;
    int v0 = 0, v1 = 0, v2 = 0, v3 = 0;
#pragma unroll
    for (int k = 0; k < 8; ++k) {
        const int* c = cnt8 + (size_t)k * N;
        if (base + 0 < N) v0 += c[base + 0];
        if (base + 1 < N) v1 += c[base + 1];
        if (base + 2 < N) v2 += c[base + 2];
        if (base + 3 < N) v3 += c[base + 3];
    }
    if (base + 0 < N) dis[base + 0] = rsqrtf((float)v0 + 1.0f);
    if (base + 1 < N) dis[base + 1] = rsqrtf((float)v1 + 1.0f);
    if (base + 2 < N) dis[base + 2] = rsqrtf((float)v2 + 1.0f);
    if (base + 3 < N) dis[base + 3] = rsqrtf((float)v3 + 1.0f);
    int tot = v0 + v1 + v2 + v3;
    sdata[t] = tot;
    __syncthreads();
    for (int o = 1; o < 256; o <<= 1) {
        int x = (t >= o) ? sdata[t - o] : 0;
        __syncthreads();
        sdata[t] += x;
        __syncthreads();
    }
    int incl = sdata[t];
    int eb = incl - tot;
    if (base + 0 < N) excl[base + 0] = eb;
    if (base + 1 < N) excl[base + 1] = eb + v0;
    if (base + 2 < N) excl[base + 2] = eb + v0 + v1;
    if (base + 3 < N) excl[base + 3] = eb + v0 + v1 + v2;
    if (t == 255) blksum[blockIdx.x] = incl;
}

// scan2 fused in: every block redoes the <=64-elem blksum exclusive scan locally.
__global__ void scan23_kernel(int* __restrict__ excl, int* __restrict__ cursor,
                              const int* __restrict__ blksum, int nb, int N, int E) {
    __shared__ int sblk[64];
    int t = threadIdx.x;
    if (t < 64) {                 // threads 0..63 = wave 0
        int orig = (t < nb) ? blksum[t] : 0;
        int v = orig;
        for (int o = 1; o < 64; o <<= 1) { int x = __shfl_up(v, o); if (t >= o) v += x; }
        sblk[t] = v - orig;       // exclusive base
    }
    __syncthreads();
    int i = blockIdx.x * 256 + t;
    if (i < N) {
        int v = excl[i] + sblk[i >> 10];
        excl[i] = v;
        cursor[i] = v;
    }
    if (i == 0) excl[N] = E;
}

// XCD-partitioned CSR fill (part = blockIdx&7 owns one dest range).
__global__ void fill_kernel(const int* __restrict__ ei, int E, int PART,
                            int* __restrict__ cursor, int* __restrict__ csr_col) {
    int part = blockIdx.x & 7;
    int e = (blockIdx.x >> 3) * 256 + threadIdx.x;
    if (e >= E) return;
    int r = ei[e];
    int lo = part * PART;
    if (r < lo || r >= lo + PART) return;
    int c = ei[E + e];
    int pos = atomicAdd(&cursor[r], 1);
    csr_col[pos] = c;
}

// -------- MFMA GEMM: out16[N][128] = fp16( A[N][128] @ W[128][128] ) --------
// Wt is fp16 pre-transposed [n][k]. Block = 256 thr = 4 waves, 64 rows.
// LDS: Wt staged padded (stride 136 fp16) -> conflict-min ds_read_b128;
// epilogue reuses the same LDS for coalesced fp16 stores.

template <int AF32>
__global__ __launch_bounds__(256) void gemm_mfma(const void* __restrict__ Ain,
                                                 const _Float16* __restrict__ Wt,
                                                 _Float16* __restrict__ out, int N) {
    __shared__ _Float16 smem[128 * 136];    // 34816 B; aliased: sWt then sOut
    _Float16* sWt = smem;
    _Float16* sOut = smem;
    const int t = threadIdx.x;
    const int w = t >> 6, l = t & 63;
    const int l15 = l & 15, kgrp = l >> 4;
    const int brow = blockIdx.x * 64;

    // stage Wt (16384 fp16 = 2048 granules of 8): 8 granules per thread
#pragma unroll
    for (int i = 0; i < 8; ++i) {
        int g = t + i * 256;
        int n = g >> 4, kg = g & 15;
        *(half8v*)&sWt[n * 136 + kg * 8] = *(const half8v*)&Wt[n * 128 + kg * 8];
    }
    __syncthreads();

    int arow = brow + w * 16 + l15;
    f32x4 acc[8];
#pragma unroll
    for (int ct = 0; ct < 8; ++ct) acc[ct] = (f32x4){0.f, 0.f, 0.f, 0.f};

#pragma unroll
    for (int kt = 0; kt < 4; ++kt) {
        int kb = kt * 32 + kgrp * 8;
        half8v af;
        if (AF32) {
            const float* A = (const float*)Ain;
            if (arow < N) {
                float4 x0 = *(const float4*)&A[(size_t)arow * 128 + kb];
                float4 x1 = *(const float4*)&A[(size_t)arow * 128 + kb + 4];
                af = (half8v){(_Float16)x0.x, (_Float16)x0.y, (_Float16)x0.z, (_Float16)x0.w,
                              (_Float16)x1.x, (_Float16)x1.y, (_Float16)x1.z, (_Float16)x1.w};
            } else af = (half8v)0;
        } else {
            const _Float16* A = (const _Float16*)Ain;
            af = (arow < N) ? *(const half8v*)&A[(size_t)arow * 128 + kb] : (half8v)0;
        }
#pragma unroll
        for (int ct = 0; ct < 8; ++ct) {
            half8v bf = *(const half8v*)&sWt[(ct * 16 + l15) * 136 + kb];
            acc[ct] = __builtin_amdgcn_mfma_f32_16x16x32_f16(af, bf, acc[ct], 0, 0, 0);
        }
    }
    __syncthreads();   // all sWt reads done; reuse LDS as sOut

    // C/D layout: col = lane&15, row = (lane>>4)*4 + reg  [guide-verified]
#pragma unroll
    for (int ct = 0; ct < 8; ++ct) {
#pragma unroll
        for (int r = 0; r < 4; ++r) {
            sOut[(w * 16 + kgrp * 4 + r) * 136 + ct * 16 + l15] = (_Float16)acc[ct][r];
        }
    }
    __syncthreads();

    // coalesced store: 64 rows x 128 fp16 = 1024 granules of 8; 4 per thread
#pragma unroll
    for (int i = 0; i < 4; ++i) {
        int g = t + i * 256;
        int row = g >> 4, c16 = g & 15;
        int grow = brow + row;
        if (grow < N)
            *(half8v*)&out[(size_t)grow * 128 + c16 * 8] =
                *(const half8v*)&sOut[row * 136 + c16 * 8];
    }
}

// -------- GEMM: out[N][16] = A16[N][128] @ W[128][16]  (VALU, A fp16) --------

__global__ __launch_bounds__(256) void gemm_nk16(const _Float16* __restrict__ A,
                                                 const float* __restrict__ W,
                                                 float* __restrict__ out, int N) {
    __shared__ float sW[128][16];    // 8 KB
    __shared__ float sA[32][132];    // padded, 16.5 KB
    int t = threadIdx.x;
#pragma unroll
    for (int i = 0; i < 2; ++i) {
        int idx = t + i * 256;       // 512 float4s over 2048 floats
        *(float4*)&sW[idx >> 2][(idx & 3) * 4] = *(const float4*)&W[idx * 4];
    }
    int brow = blockIdx.x * 32;
#pragma unroll
    for (int i = 0; i < 2; ++i) {
        int g = t + i * 256;         // 512 granules of 8 fp16
        int rr = g >> 4, c8 = g & 15;
        int grow = brow + rr;
        half8v v = (half8v)0;
        if (grow < N) v = *(const half8v*)&A[(size_t)grow * 128 + c8 * 8];
        float4 f0 = make_float4((float)v.s0, (float)v.s1, (float)v.s2, (float)v.s3);
        float4 f1 = make_float4((float)v.s4, (float)v.s5, (float)v.s6, (float)v.s7);
        *(float4*)&sA[rr][c8 * 8] = f0;
        *(float4*)&sA[rr][c8 * 8 + 4] = f1;
    }
    __syncthreads();
    int r = t >> 3;       // 0..31
    int cg = t & 7;       // cols cg*2, cg*2+1
    float a0 = 0.f, a1 = 0.f;
#pragma unroll
    for (int k = 0; k < 128; ++k) {
        float a = sA[r][k];
        float2 w = *(const float2*)&sW[k][cg * 2];
        a0 = fmaf(a, w.x, a0);
        a1 = fmaf(a, w.y, a1);
    }
    int g = brow + r;
    if (g < N) {
        out[(size_t)g * 16 + cg * 2 + 0] = a0;
        out[(size_t)g * 16 + cg * 2 + 1] = a1;
    }
}

// ----- aggregation (128 wide), fp16 table in, fp16 out; fp32 accumulate -----

__global__ __launch_bounds__(256) void agg128_kernel(const _Float16* __restrict__ t,
        const int* __restrict__ csr_col,
        const int* __restrict__ offset, const float* __restrict__ dis,
        const float* __restrict__ bias, _Float16* __restrict__ out, int N, int do_relu) {
    int node = blockIdx.x * 4 + (threadIdx.x >> 6);
    if (node >= N) return;
    int lane = threadIdx.x & 63;
    int half = lane >> 5;
    int col4 = (lane & 31) * 4;
    float dn = dis[node];

    half4v sv = *(const half4v*)&t[(size_t)node * 128 + col4];
    float sw = half ? 0.0f : dn * dn;
    float4 acc;
    acc.x = sw * (float)sv.x; acc.y = sw * (float)sv.y;
    acc.z = sw * (float)sv.z; acc.w = sw * (float)sv.w;

    int s = offset[node], e = offset[node + 1];
    int j = s + half;
    for (; j + 6 < e; j += 8) {
        int c0 = csr_col[j];
        int c1 = csr_col[j + 2];
        int c2 = csr_col[j + 4];
        int c3 = csr_col[j + 6];
        half4v v0 = *(const half4v*)&t[(size_t)c0 * 128 + col4];
        half4v v1 = *(const half4v*)&t[(size_t)c1 * 128 + col4];
        half4v v2 = *(const half4v*)&t[(size_t)c2 * 128 + col4];
        half4v v3 = *(const half4v*)&t[(size_t)c3 * 128 + col4];
        float w0 = dn * dis[c0];
        float w1 = dn * dis[c1];
        float w2 = dn * dis[c2];
        float w3 = dn * dis[c3];
        acc.x = fmaf(w0, (float)v0.x, acc.x); acc.y = fmaf(w0, (float)v0.y, acc.y);
        acc.z = fmaf(w0, (float)v0.z, acc.z); acc.w = fmaf(w0, (float)v0.w, acc.w);
        acc.x = fmaf(w1, (float)v1.x, acc.x); acc.y = fmaf(w1, (float)v1.y, acc.y);
        acc.z = fmaf(w1, (float)v1.z, acc.z); acc.w = fmaf(w1, (float)v1.w, acc.w);
        acc.x = fmaf(w2, (float)v2.x, acc.x); acc.y = fmaf(w2, (float)v2.y, acc.y);
        acc.z = fmaf(w2, (float)v2.z, acc.z); acc.w = fmaf(w2, (float)v2.w, acc.w);
        acc.x = fmaf(w3, (float)v3.x, acc.x); acc.y = fmaf(w3, (float)v3.y, acc.y);
        acc.z = fmaf(w3, (float)v3.z, acc.z); acc.w = fmaf(w3, (float)v3.w, acc.w);
    }
    for (; j < e; j += 2) {
        int c = csr_col[j];
        half4v v = *(const half4v*)&t[(size_t)c * 128 + col4];
        float w = dn * dis[c];
        acc.x = fmaf(w, (float)v.x, acc.x); acc.y = fmaf(w, (float)v.y, acc.y);
        acc.z = fmaf(w, (float)v.z, acc.z); acc.w = fmaf(w, (float)v.w, acc.w);
    }
    acc.x += __shfl_xor(acc.x, 32);
    acc.y += __shfl_xor(acc.y, 32);
    acc.z += __shfl_xor(acc.z, 32);
    acc.w += __shfl_xor(acc.w, 32);
    if (half == 0) {
        float4 b = *(const float4*)&bias[col4];
        float ox = acc.x + b.x, oy = acc.y + b.y, oz = acc.z + b.z, ow = acc.w + b.w;
        if (do_relu) {
            ox = fmaxf(ox, 0.f); oy = fmaxf(oy, 0.f);
            oz = fmaxf(oz, 0.f); ow = fmaxf(ow, 0.f);
        }
        half4v o = {(_Float16)ox, (_Float16)oy, (_Float16)oz, (_Float16)ow};
        *(half4v*)&out[(size_t)node * 128 + col4] = o;
    }
}

// ------- aggregation (16 wide) + bias + log_softmax: 16 lanes per node -------

__global__ __launch_bounds__(256) void agg16_ls_kernel(const float* __restrict__ t2,
        const int* __restrict__ csr_col,
        const int* __restrict__ offset, const float* __restrict__ dis,
        const float* __restrict__ b2, float* __restrict__ out, int N) {
    int gid = blockIdx.x * 256 + threadIdx.x;
    int node = gid >> 4;
    int c = gid & 15;
    if (node >= N) return;
    float dn = dis[node];
    float acc = dn * dn * t2[(size_t)node * 16 + c];
    int s = offset[node], e = offset[node + 1];
    for (int j = s; j < e; ++j) {
        int col = csr_col[j];
        float w = dn * dis[col];
        acc = fmaf(w, t2[(size_t)col * 16 + c], acc);
    }
    float v = acc + b2[c];
    float m = v;
#pragma unroll
    for (int o = 1; o < 16; o <<= 1) m = fmaxf(m, __shfl_xor(m, o, 16));
    float ex = expf(v - m);
    float ssum = ex;
#pragma unroll
    for (int o = 1; o < 16; o <<= 1) ssum += __shfl_xor(ssum, o, 16);
    out[(size_t)node * 16 + c] = v - m - logf(ssum);
}

// ---------------------------------- launch ----------------------------------

extern "C" void kernel_launch(void* const* d_in, const int* in_sizes, int n_in,
                              void* d_out, int out_size, void* d_ws, size_t ws_size,
                              hipStream_t stream) {
    const float* x  = (const float*)d_in[0];
    const int*   ei = (const int*)d_in[1];
    const float* W0 = (const float*)d_in[2];
    const float* b0 = (const float*)d_in[3];
    const float* W1 = (const float*)d_in[4];
    const float* b1 = (const float*)d_in[5];
    const float* W2 = (const float*)d_in[6];
    const float* b2 = (const float*)d_in[7];
    int N = in_sizes[0] / 128;
    int E = in_sizes[1] / 2;
    int PART = (N + 7) / 8;
    float* out = (float*)d_out;

    char* ws = (char*)d_ws;
    size_t off = 0;
    auto alloc = [&](size_t bytes) -> void* {
        void* p = ws + off;
        off = (off + bytes + 255) & ~(size_t)255;
        return p;
    };
    _Float16* t16  = (_Float16*)alloc((size_t)N * 128 * 2);
    _Float16* tB16 = (_Float16*)alloc((size_t)N * 128 * 2);
    float* t2      = (float*)alloc((size_t)N * 16 * 4);
    int*   cnt8    = (int*)alloc((size_t)N * 8 * 4);
    int*   offs    = (int*)alloc((size_t)(N + 1) * 4);
    int*   cursor  = (int*)alloc((size_t)N * 4);
    int*   blksum  = (int*)alloc(64 * 4);
    float* dis     = (float*)alloc((size_t)N * 4);
    int*   csr_col = (int*)alloc((size_t)E * 4);
    _Float16* Wt0  = (_Float16*)alloc(128 * 128 * 2);
    _Float16* Wt1  = (_Float16*)alloc(128 * 128 * 2);

    int n4 = (int)(((size_t)N * 8) / 4);
    setup_kernel<<<400, 256, 0, stream>>>(W0, W1, Wt0, Wt1, (int4*)cnt8, n4);

    int nchunk = (E + 255) / 256;
    int nb = (N + 1023) / 1024;   // 49 for N=50000 (must be <= 64)
    count_kernel<<<nchunk, 256, 0, stream>>>(ei, cnt8, N, E);
    scan1_kernel<<<nb, 256, 0, stream>>>(cnt8, offs, blksum, dis, N);
    scan23_kernel<<<(N + 255) / 256, 256, 0, stream>>>(offs, cursor, blksum, nb, N, E);
    fill_kernel<<<nchunk * 8, 256, 0, stream>>>(ei, E, PART, cursor, csr_col);

    int gemm_blocks = (N + 63) / 64;
    int agg_blocks  = (N + 3) / 4;

    gemm_mfma<1><<<gemm_blocks, 256, 0, stream>>>(x, Wt0, t16, N);
    agg128_kernel<<<agg_blocks, 256, 0, stream>>>(t16, csr_col, offs, dis, b0, tB16, N, 1);
    gemm_mfma<0><<<gemm_blocks, 256, 0, stream>>>(tB16, Wt1, t16, N);
    agg128_kernel<<<agg_blocks, 256, 0, stream>>>(t16, csr_col, offs, dis, b1, tB16, N, 1);
    gemm_nk16<<<(N + 31) / 32, 256, 0, stream>>>(tB16, W2, t2, N);
    agg16_ls_kernel<<<(int)(((size_t)N * 16 + 255) / 256), 256, 0, stream>>>(
        t2, csr_col, offs, dis, b2, out, N);
}